// Round 3
// baseline (311.947 us; speedup 1.0000x reference)
//
#include <hip/hip_runtime.h>
#include <hip/hip_bf16.h>

typedef unsigned short u16;
typedef unsigned int u32;
typedef __bf16 bf16x8 __attribute__((ext_vector_type(8)));
typedef float floatx4 __attribute__((ext_vector_type(4)));

#define T_SEQ 2048
#define HDIM 64
#define NBH 32   // B*H

static __device__ __forceinline__ u16 f2b_rne(float x) {
    union { float f; u32 u; } c; c.f = x;
    u32 u = c.u;
    return (u16)((u + 0x7fffu + ((u >> 16) & 1u)) >> 16);
}
static __device__ __forceinline__ u16 f2b_trunc(float x) {
    union { float f; u32 u; } c; c.f = x;
    return (u16)(c.u >> 16);
}
static __device__ __forceinline__ u32 pack2(float a, float b) {
    union { __hip_bfloat162 h; u32 u; } cv;
    cv.h = __float22bfloat162_rn(make_float2(a, b));   // a -> low16, b -> high16
    return cv.u;
}
// additive block swizzle, consistent on write & read sides
#define SW(blk, row) (((blk) + ((row) >> 3) + ((row) & 7)) & 7)

struct Pref { float4 k0, k1, k2, k3, va, vb, vc, vd; };

static __device__ __forceinline__ void stage_load(const float* __restrict__ kg,
                                                  const float* __restrict__ vg,
                                                  int koff, int voff, Pref& p) {
    const float* kr = kg + koff;
    p.k0 = *(const float4*)(kr + 0);
    p.k1 = *(const float4*)(kr + 4);
    p.k2 = *(const float4*)(kr + 8);
    p.k3 = *(const float4*)(kr + 12);
    const float* vr = vg + voff;
    p.va = *(const float4*)(vr + 0);
    p.vb = *(const float4*)(vr + 4);
    p.vc = *(const float4*)(vr + HDIM);
    p.vd = *(const float4*)(vr + HDIM + 4);
}

static __device__ __forceinline__ void stage_store(const Pref& p, u16* Kd, u16* Vd,
                                                   int tid) {
    // K: thread owns row rk, 16 d at (tid&3)*16 -> two swizzled b128 writes
    const int rk = tid >> 2, kq = tid & 3;
    uint4 w0, w1;
    w0.x = pack2(p.k0.x, p.k0.y); w0.y = pack2(p.k0.z, p.k0.w);
    w0.z = pack2(p.k1.x, p.k1.y); w0.w = pack2(p.k1.z, p.k1.w);
    w1.x = pack2(p.k2.x, p.k2.y); w1.y = pack2(p.k2.z, p.k2.w);
    w1.z = pack2(p.k3.x, p.k3.y); w1.w = pack2(p.k3.z, p.k3.w);
    *(uint4*)(Kd + rk * 64 + SW(kq * 2 + 0, rk) * 8) = w0;
    *(uint4*)(Kd + rk * 64 + SW(kq * 2 + 1, rk) * 8) = w1;

    // V transpose: thread owns t-pair (2tp, 2tp+1) x 8 d; pack t-pairs into
    // b32 writes at Vt[d][t]. Banks: (vblk+dg+ii) spreads 8 groups -> 2-way.
    const int tp = tid >> 3, dg = tid & 7;
    const int vblk = tp >> 2, dw = tp & 3;
    u32* V32 = (u32*)Vd;
#define VW(ii, LO, HI) \
    V32[(dg * 8 + (ii)) * 32 + (((vblk) + dg + (ii)) & 7) * 4 + dw] = pack2(LO, HI)
    VW(0, p.va.x, p.vc.x); VW(1, p.va.y, p.vc.y);
    VW(2, p.va.z, p.vc.z); VW(3, p.va.w, p.vc.w);
    VW(4, p.vb.x, p.vd.x); VW(5, p.vb.y, p.vd.y);
    VW(6, p.vb.z, p.vd.z); VW(7, p.vb.w, p.vd.w);
#undef VW
}

// grid (bh=32, s=32), 256 threads = 4 waves; wave owns 16 q rows.
// qt = balance-map(s): each CU's 4 co-resident blocks sum to 66 iterations.
__global__ __launch_bounds__(256, 4) void fattn(const float* __restrict__ q,
                                                const float* __restrict__ k,
                                                const float* __restrict__ v,
                                                float* __restrict__ out) {
    __shared__ __align__(16) u16 Kl[2][64 * 64];   // [key][d] swizzled, dbuf
    __shared__ __align__(16) u16 Vl[2][64 * 64];   // [d][key] swizzled, dbuf
    __shared__ __align__(16) u16 Pl[4][16 * 64];   // per-wave P

    const int bh = blockIdx.x;
    const int s = blockIdx.y;
    const int qt = (s & 8) ? (s ^ 7) : s;          // bijective, cousin-balanced
    const int tid = threadIdx.x;
    const int wave = tid >> 6, lane = tid & 63;
    const int l15 = lane & 15, quad = lane >> 4;

    const float* qp = q + (size_t)bh * T_SEQ * HDIM;
    const float* kp = k + (size_t)bh * T_SEQ * HDIM;
    const float* vp = v + (size_t)bh * T_SEQ * HDIM;

    const int qrow_base = qt * 64 + wave * 16;
    const int koff = (tid >> 2) * HDIM + (tid & 3) * 16;
    const int voff = (tid >> 3) * 2 * HDIM + (tid & 7) * 8;

    // prologue: stage tile 0 into buffer 0
    Pref p0;
    stage_load(kp, vp, koff, voff, p0);

    // Q fragments (A-layout), pre-scaled by scale*log2(e)
    const float SL2E = 0.125f * 1.44269504088896f;
    bf16x8 qf[2];
    {
        const float* qrow = qp + (size_t)(qrow_base + l15) * HDIM;
#pragma unroll
        for (int kc = 0; kc < 2; kc++) {
            const float4* p4 = (const float4*)(qrow + kc * 32 + quad * 8);
            float4 fa = p4[0], fb = p4[1];
            union { bf16x8 v; u16 s[8]; } cv;
            cv.s[0] = f2b_rne(fa.x * SL2E); cv.s[1] = f2b_rne(fa.y * SL2E);
            cv.s[2] = f2b_rne(fa.z * SL2E); cv.s[3] = f2b_rne(fa.w * SL2E);
            cv.s[4] = f2b_rne(fb.x * SL2E); cv.s[5] = f2b_rne(fb.y * SL2E);
            cv.s[6] = f2b_rne(fb.z * SL2E); cv.s[7] = f2b_rne(fb.w * SL2E);
            qf[kc] = cv.v;
        }
    }
    stage_store(p0, Kl[0], Vl[0], tid);

    floatx4 o_acc[4];
    float lsum[4] = {0.f, 0.f, 0.f, 0.f};
#pragma unroll
    for (int t = 0; t < 4; t++) o_acc[t] = (floatx4){0.f, 0.f, 0.f, 0.f};
    u16* pw = &Pl[wave][0];

    for (int j = 0; j <= qt; ++j) {
        const int cur = j & 1;
        __syncthreads();   // buf[cur] ready

        // prefetch next fp32 tile into registers (after barrier)
        Pref pn;
        const bool pre = (j < qt);
        if (pre)
            stage_load(kp + (size_t)(j + 1) * 64 * HDIM,
                       vp + (size_t)(j + 1) * 64 * HDIM, koff, voff, pn);

        // S = Q K^T, z already in exp2 domain
        floatx4 sacc[4];
#pragma unroll
        for (int t = 0; t < 4; t++) sacc[t] = (floatx4){0.f, 0.f, 0.f, 0.f};
        const u16* Kc = Kl[cur];
#pragma unroll
        for (int kc = 0; kc < 2; kc++) {
#pragma unroll
            for (int t = 0; t < 4; t++) {
                int rk = t * 16 + l15;
                bf16x8 bf = *(const bf16x8*)(Kc + rk * 64 + SW(kc * 4 + quad, rk) * 8);
                sacc[t] = __builtin_amdgcn_mfma_f32_16x16x32_bf16(qf[kc], bf, sacc[t], 0, 0, 0);
            }
        }

        // P = exp2(z) in place; causal mask only on diagonal tile
        if (j == qt) {
            const int grow = qrow_base + quad * 4;
#pragma unroll
            for (int t = 0; t < 4; t++) {
                int gcol = j * 64 + t * 16 + l15;
#pragma unroll
                for (int rg = 0; rg < 4; rg++) {
                    float e = __builtin_amdgcn_exp2f(sacc[t][rg]);
                    sacc[t][rg] = (gcol > grow + rg) ? 0.f : e;
                }
            }
        } else {
#pragma unroll
            for (int t = 0; t < 4; t++)
#pragma unroll
                for (int rg = 0; rg < 4; rg++)
                    sacc[t][rg] = __builtin_amdgcn_exp2f(sacc[t][rg]);
        }

#pragma unroll
        for (int rg = 0; rg < 4; rg++)
            lsum[rg] += (sacc[0][rg] + sacc[1][rg]) + (sacc[2][rg] + sacc[3][rg]);

        // P (C-layout) -> LDS A-source layout
#pragma unroll
        for (int t = 0; t < 4; t++) {
#pragma unroll
            for (int rg = 0; rg < 4; rg++) {
                int r = quad * 4 + rg;
                int c = t * 16 + l15;
                pw[r * 64 + (((c >> 3) ^ (r & 7)) * 8) + (c & 7)] = f2b_trunc(sacc[t][rg]);
            }
        }
        asm volatile("s_waitcnt lgkmcnt(0)" ::: "memory");

        // O += P V
        const u16* Vc = Vl[cur];
#pragma unroll
        for (int kc = 0; kc < 2; kc++) {
            int bm = (kc * 4 + quad) ^ (l15 & 7);
            bf16x8 af = *(const bf16x8*)(&pw[l15 * 64 + bm * 8]);
#pragma unroll
            for (int t = 0; t < 4; t++) {
                int rv = t * 16 + l15;
                bf16x8 bfv = *(const bf16x8*)(Vc + rv * 64 + SW(kc * 4 + quad, rv) * 8);
                o_acc[t] = __builtin_amdgcn_mfma_f32_16x16x32_bf16(af, bfv, o_acc[t], 0, 0, 0);
            }
        }

        // tail: convert + commit prefetched tile to other buffer
        if (pre) stage_store(pn, Kl[cur ^ 1], Vl[cur ^ 1], tid);
    }

    // epilogue: one 16-lane reduction per row, then O/l
    float* op = out + (size_t)bh * T_SEQ * HDIM;
#pragma unroll
    for (int rg = 0; rg < 4; rg++) {
        float ssum = lsum[rg];
#pragma unroll
        for (int off = 1; off < 16; off <<= 1)
            ssum += __shfl_xor(ssum, off, 64);
        float inv = 1.0f / ssum;
        size_t row = (size_t)(qrow_base + quad * 4 + rg) * HDIM;
#pragma unroll
        for (int t = 0; t < 4; t++)
            op[row + t * 16 + l15] = o_acc[t][rg] * inv;
    }
}

extern "C" void kernel_launch(void* const* d_in, const int* in_sizes, int n_in,
                              void* d_out, int out_size, void* d_ws, size_t ws_size,
                              hipStream_t stream) {
    const float* q = (const float*)d_in[0];
    const float* k = (const float*)d_in[1];
    const float* v = (const float*)d_in[2];
    float* out = (float*)d_out;
    fattn<<<dim3(NBH, T_SEQ / 64), 256, 0, stream>>>(q, k, v, out);
}

// Round 4
// 168.583 us; speedup vs baseline: 1.8504x; 1.8504x over previous
//
#include <hip/hip_runtime.h>
#include <hip/hip_bf16.h>

typedef unsigned short u16;
typedef unsigned int u32;
typedef __bf16 bf16x8 __attribute__((ext_vector_type(8)));
typedef short s16x4 __attribute__((ext_vector_type(4)));
typedef float floatx4 __attribute__((ext_vector_type(4)));

#define T_SEQ 2048
#define HDIM 64
#define NBH 32   // B*H

static __device__ __forceinline__ u16 f2b_rne(float x) {
    union { float f; u32 u; } c; c.f = x;
    u32 u = c.u;
    return (u16)((u + 0x7fffu + ((u >> 16) & 1u)) >> 16);
}
static __device__ __forceinline__ u16 f2b_trunc(float x) {
    union { float f; u32 u; } c; c.f = x;
    return (u16)(c.u >> 16);
}

// ---- prepass (round-2 proven): K fp32->bf16 flat; V fp32->bf16 transposed ----
__global__ __launch_bounds__(256) void prep(const float* __restrict__ k,
                                            const float* __restrict__ v,
                                            u16* __restrict__ kb,
                                            u16* __restrict__ vt) {
    __shared__ u16 tile[64][68];
    const int bh = blockIdx.y, t0 = blockIdx.x * 64;
    const int tid = threadIdx.x;

    const float* ksrc = k + ((size_t)bh * T_SEQ + t0) * HDIM;
    u16* kdst = kb + ((size_t)bh * T_SEQ + t0) * HDIM;
#pragma unroll
    for (int p = 0; p < 4; p++) {
        int idx = p * 256 + tid;
        float4 f = ((const float4*)ksrc)[idx];
        ushort4 o;
        o.x = f2b_rne(f.x); o.y = f2b_rne(f.y); o.z = f2b_rne(f.z); o.w = f2b_rne(f.w);
        ((ushort4*)kdst)[idx] = o;
    }

    const float* vsrc = v + ((size_t)bh * T_SEQ + t0) * HDIM;
#pragma unroll
    for (int p = 0; p < 4; p++) {
        int idx = p * 256 + tid;
        int r = idx >> 4, c4 = (idx & 15) * 4;
        float4 f = *(const float4*)(vsrc + r * HDIM + c4);
        tile[c4 + 0][r] = f2b_rne(f.x);
        tile[c4 + 1][r] = f2b_rne(f.y);
        tile[c4 + 2][r] = f2b_rne(f.z);
        tile[c4 + 3][r] = f2b_rne(f.w);
    }
    __syncthreads();
    u16* dst = vt + (size_t)bh * HDIM * T_SEQ + t0;
#pragma unroll
    for (int p = 0; p < 4; p++) {
        int idx = p * 256 + tid;
        int d = idx >> 4, c4 = (idx & 15) * 4;
        *(ushort4*)(dst + (size_t)d * T_SEQ + c4) = *(ushort4*)(&tile[d][c4]);
    }
}

// ---- main kernel ----
// grid (bh=32, s=32); qt = balance-map(s): every CU's 4 co-resident blocks
// sum to 66 iterations. 4 waves; wave owns 16 q rows.
// Computes S^T = K·Q^T so the QK^T C-fragment IS the PV A-fragment (K=16):
// no P round-trip through LDS.
__global__ __launch_bounds__(256, 4) void fattn(const float* __restrict__ q,
                                                const u16* __restrict__ kb,
                                                const u16* __restrict__ vtb,
                                                float* __restrict__ out) {
    __shared__ __align__(16) u16 Kl[2][64 * 64];   // [key][d], XOR-swizzled
    __shared__ __align__(16) u16 Vl[2][64 * 64];   // [d][key], slot-swizzled

    const int bh = blockIdx.x;
    const int s = blockIdx.y;
    const int qt = (s & 8) ? (s ^ 7) : s;          // bijective, cousin-balanced
    const int tid = threadIdx.x;
    const int wave = tid >> 6, lane = tid & 63;
    const int l15 = lane & 15, quad = lane >> 4;

    const float* qp = q + (size_t)bh * T_SEQ * HDIM;
    const u16* kp = kb + (size_t)bh * T_SEQ * HDIM;
    const u16* vp = vtb + (size_t)bh * HDIM * T_SEQ;

    const int qrow_base = qt * 64 + wave * 16;

    // K staging: thread owns rows r0, r0+32 x 8 d at blk*8 (XOR swizzle)
    const int r0 = tid >> 3, blk = tid & 7;
    const int bsw = blk ^ (r0 & 7);
    const u16* kbase = kp + r0 * HDIM + blk * 8;
    const int kls0 = r0 * 64 + bsw * 8;
    const int kls1 = kls0 + 32 * 64;

    // V staging: thread owns d-row vd, key-blocks vkb and vkb+4 (8 keys each).
    // LDS slot for key-block b at row d: (b + (d&7)) & 7  (16B slots).
    const int vd = tid >> 2, vkb = tid & 3;
    const u16* vbase = vp + (size_t)vd * T_SEQ;
    const int vls0 = vd * 64 + (((vkb + 0) + (vd & 7)) & 7) * 8;
    const int vls1 = vd * 64 + (((vkb + 4) + (vd & 7)) & 7) * 8;

    struct Pref { uint4 k0, k1, v0, v1; };
    auto stage_load = [&](int j, Pref& p) {
        const u16* kj = kbase + (size_t)j * 64 * HDIM;
        p.k0 = *(const uint4*)(kj);
        p.k1 = *(const uint4*)(kj + 32 * HDIM);
        const u16* vj = vbase + j * 64;
        p.v0 = *(const uint4*)(vj + vkb * 8);
        p.v1 = *(const uint4*)(vj + vkb * 8 + 32);
    };
    auto stage_store = [&](const Pref& p, u16* Kd, u16* Vd) {
        *(uint4*)(Kd + kls0) = p.k0;
        *(uint4*)(Kd + kls1) = p.k1;
        *(uint4*)(Vd + vls0) = p.v0;
        *(uint4*)(Vd + vls1) = p.v1;
    };

    Pref p0;
    stage_load(0, p0);

    // Q fragments (A/B-layout identical): lane l15 holds Q[row][kc*32+quad*8..+7],
    // pre-scaled by scale*log2(e)
    const float SL2E = 0.125f * 1.44269504088896f;
    bf16x8 qf[2];
    {
        const float* qrow = qp + (size_t)(qrow_base + l15) * HDIM;
#pragma unroll
        for (int kc = 0; kc < 2; kc++) {
            const float4* p4 = (const float4*)(qrow + kc * 32 + quad * 8);
            float4 fa = p4[0], fb = p4[1];
            union { bf16x8 v; u16 s[8]; } cv;
            cv.s[0] = f2b_rne(fa.x * SL2E); cv.s[1] = f2b_rne(fa.y * SL2E);
            cv.s[2] = f2b_rne(fa.z * SL2E); cv.s[3] = f2b_rne(fa.w * SL2E);
            cv.s[4] = f2b_rne(fb.x * SL2E); cv.s[5] = f2b_rne(fb.y * SL2E);
            cv.s[6] = f2b_rne(fb.z * SL2E); cv.s[7] = f2b_rne(fb.w * SL2E);
            qf[kc] = cv.v;
        }
    }
    stage_store(p0, Kl[0], Vl[0]);

    floatx4 o_acc[4];
#pragma unroll
    for (int dt = 0; dt < 4; dt++) o_acc[dt] = (floatx4){0.f, 0.f, 0.f, 0.f};
    float lsum = 0.f;                              // row-sum for qrow = l15

    // V-read slot is independent of dt (d&7 == l15&7)
    const int vhalf = (quad & 1) * 4;
    int vslot[4];
#pragma unroll
    for (int t = 0; t < 4; t++)
        vslot[t] = (((t * 2 + (quad >> 1)) + (l15 & 7)) & 7) * 8 + vhalf;

    for (int j = 0; j <= qt; ++j) {
        const int cur = j & 1;
        __syncthreads();   // buf[cur] ready

        Pref pn;
        const bool pre = (j < qt);
        if (pre) stage_load(j + 1, pn);

        // S^T = K · Q^T : A = K-frag (m=key), B = qf (n=qrow)
        floatx4 sacc[4];
#pragma unroll
        for (int t = 0; t < 4; t++) sacc[t] = (floatx4){0.f, 0.f, 0.f, 0.f};
        const u16* Kc = Kl[cur];
#pragma unroll
        for (int kc = 0; kc < 2; kc++) {
#pragma unroll
            for (int t = 0; t < 4; t++) {
                int rk = t * 16 + l15;
                bf16x8 kf = *(const bf16x8*)(Kc + rk * 64 + ((kc * 4 + quad) ^ (rk & 7)) * 8);
                sacc[t] = __builtin_amdgcn_mfma_f32_16x16x32_bf16(kf, qf[kc], sacc[t], 0, 0, 0);
            }
        }

        // P^T = exp2(S^T); causal mask on diagonal tile; pack to PV A-frags
        s16x4 pfrag[4];
        const bool diag = (j == qt);
        const int gq = wave * 16 + l15;            // q-row within 64-block
#pragma unroll
        for (int t = 0; t < 4; t++) {
            union { s16x4 v; u16 h[4]; } pk;
#pragma unroll
            for (int rg = 0; rg < 4; rg++) {
                float e = __builtin_amdgcn_exp2f(sacc[t][rg]);
                if (diag && (t * 16 + quad * 4 + rg > gq)) e = 0.f;
                lsum += e;
                pk.h[rg] = f2b_trunc(e);
            }
            pfrag[t] = pk.v;
        }

        // O += P · V : A = pfrag (from regs!), B = V-frag (b64 from LDS)
        const u16* Vc = Vl[cur];
#pragma unroll
        for (int t = 0; t < 4; t++) {
#pragma unroll
            for (int dt = 0; dt < 4; dt++) {
                int d = dt * 16 + l15;
                s16x4 vf = *(const s16x4*)(Vc + d * 64 + vslot[t]);
                o_acc[dt] = __builtin_amdgcn_mfma_f32_16x16x16bf16_1k(pfrag[t], vf, o_acc[dt], 0, 0, 0);
            }
        }

        if (pre) stage_store(pn, Kl[cur ^ 1], Vl[cur ^ 1]);
    }

    // epilogue: reduce lsum over quads (lanes l15+16k), redistribute, store
    float tot = lsum;
    tot += __shfl_xor(tot, 16, 64);
    tot += __shfl_xor(tot, 32, 64);                // lane holds sum for qrow=l15
    float* op = out + (size_t)bh * T_SEQ * HDIM;
#pragma unroll
    for (int rg = 0; rg < 4; rg++) {
        float inv = 1.0f / __shfl(tot, quad * 4 + rg, 64);
        size_t row = (size_t)(qrow_base + quad * 4 + rg) * HDIM;
#pragma unroll
        for (int dt = 0; dt < 4; dt++)
            op[row + dt * 16 + l15] = o_acc[dt][rg] * inv;
    }
}

extern "C" void kernel_launch(void* const* d_in, const int* in_sizes, int n_in,
                              void* d_out, int out_size, void* d_ws, size_t ws_size,
                              hipStream_t stream) {
    const float* q = (const float*)d_in[0];
    const float* k = (const float*)d_in[1];
    const float* v = (const float*)d_in[2];
    float* out = (float*)d_out;

    u16* kb = (u16*)d_ws;                               // 8 MB bf16 K
    u16* vt = kb + (size_t)NBH * T_SEQ * HDIM;          // 8 MB bf16 V^T

    prep<<<dim3(T_SEQ / 64, NBH), 256, 0, stream>>>(k, v, kb, vt);
    fattn<<<dim3(NBH, T_SEQ / 64), 256, 0, stream>>>(q, kb, vt, out);
}

// Round 5
// 123.548 us; speedup vs baseline: 2.5249x; 1.3645x over previous
//
#include <hip/hip_runtime.h>
#include <hip/hip_bf16.h>

typedef unsigned short u16;
typedef unsigned int u32;
typedef __bf16 bf16x8 __attribute__((ext_vector_type(8)));
typedef short s16x4 __attribute__((ext_vector_type(4)));
typedef short s16x8 __attribute__((ext_vector_type(8)));
typedef float floatx4 __attribute__((ext_vector_type(4)));

#define T_SEQ 2048
#define HDIM 64
#define NBH 32   // B*H

static __device__ __forceinline__ u16 f2b_rne(float x) {
    union { float f; u32 u; } c; c.f = x;
    u32 u = c.u;
    return (u16)((u + 0x7fffu + ((u >> 16) & 1u)) >> 16);
}
static __device__ __forceinline__ u16 f2b_trunc(float x) {
    union { float f; u32 u; } c; c.f = x;
    return (u16)(c.u >> 16);
}

// async 16B/lane global->LDS; LDS dest = wave-uniform base + lane*16
#define GLOAD_LDS16(gp, lp)                                                      \
    __builtin_amdgcn_global_load_lds(                                            \
        (const __attribute__((address_space(1))) u32*)(gp),                      \
        (__attribute__((address_space(3))) u32*)(lp), 16, 0, 0)

// ---- prepass: K fp32->bf16 flat; V fp32->bf16 transposed [BH,D,T] with
// column permutation pos(k) = qg*16 + (t>>1)*8 + (t&1)*4 + j  (within each
// 64-key window; qg=(k>>2)&3, t=k>>4, j=k&3) so PV B-frag t-pairs are
// contiguous 16B in LDS. ----
__global__ __launch_bounds__(256) void prep(const float* __restrict__ k,
                                            const float* __restrict__ v,
                                            u16* __restrict__ kb,
                                            u16* __restrict__ vt) {
    __shared__ u16 tile[64][68];
    const int bh = blockIdx.y, t0 = blockIdx.x * 64;
    const int tid = threadIdx.x;

    const float* ksrc = k + ((size_t)bh * T_SEQ + t0) * HDIM;
    u16* kdst = kb + ((size_t)bh * T_SEQ + t0) * HDIM;
#pragma unroll
    for (int p = 0; p < 4; p++) {
        int idx = p * 256 + tid;
        float4 f = ((const float4*)ksrc)[idx];
        ushort4 o;
        o.x = f2b_rne(f.x); o.y = f2b_rne(f.y); o.z = f2b_rne(f.z); o.w = f2b_rne(f.w);
        ((ushort4*)kdst)[idx] = o;
    }

    const float* vsrc = v + ((size_t)bh * T_SEQ + t0) * HDIM;
#pragma unroll
    for (int p = 0; p < 4; p++) {
        int idx = p * 256 + tid;
        int r = idx >> 4, c4 = (idx & 15) * 4;
        float4 f = *(const float4*)(vsrc + r * HDIM + c4);
        tile[c4 + 0][r] = f2b_rne(f.x);
        tile[c4 + 1][r] = f2b_rne(f.y);
        tile[c4 + 2][r] = f2b_rne(f.z);
        tile[c4 + 3][r] = f2b_rne(f.w);
    }
    __syncthreads();
    u16* dst = vt + (size_t)bh * HDIM * T_SEQ + t0;
#pragma unroll
    for (int p = 0; p < 4; p++) {
        int idx = p * 256 + tid;
        int d = idx >> 4, c4 = (idx & 15) * 4;
        int t = c4 >> 4, qg = (c4 >> 2) & 3;
        int pos = qg * 16 + (t >> 1) * 8 + (t & 1) * 4;
        *(ushort4*)(dst + (size_t)d * T_SEQ + pos) = *(ushort4*)(&tile[d][c4]);
    }
}

// ---- main kernel ----
// grid (bh=32, s=32); qt = balance-map(s): every CU's 4 co-resident blocks sum
// to 66 iterations. S^T = K·Q^T so QK^T C-frag IS the PV A-frag (no P LDS
// round-trip). Staging via async global_load_lds (no VGPRs, un-sinkable),
// double-buffered; swizzles folded into per-lane SOURCE addresses.
__global__ __launch_bounds__(256, 4) void fattn(const float* __restrict__ q,
                                                const u16* __restrict__ kb,
                                                const u16* __restrict__ vtb,
                                                float* __restrict__ out) {
    __shared__ __align__(16) u16 Kl[2][64 * 64];   // [key][d], XOR slot swizzle
    __shared__ __align__(16) u16 Vl[2][64 * 64];   // [d][perm-key], +d slot swizzle

    const int bh = blockIdx.x;
    const int s = blockIdx.y;
    const int qt = (s & 8) ? (s ^ 7) : s;          // bijective, cousin-balanced
    const int tid = threadIdx.x;
    const int wave = tid >> 6, lane = tid & 63;
    const int l15 = lane & 15, quad = lane >> 4;

    const float* qp = q + (size_t)bh * T_SEQ * HDIM;
    const u16* kp = kb + (size_t)bh * T_SEQ * HDIM;
    const u16* vp = vtb + (size_t)bh * HDIM * T_SEQ;

    const int qrow_base = qt * 64 + wave * 16;

    // staging: lane covers LDS bytes [wave*1024 + lane*16] (+4096 for issue 1)
    // = row (wave*8 + (lane>>3)) (+32), slot (lane&7). Source picked so that
    // LDS slot b at row r holds: K block b^(r&7); V perm-slot (b-r)&7.
    const int srow = wave * 8 + (lane >> 3);
    const int slot = lane & 7;
    const u16* kg0 = kp + srow * HDIM + (slot ^ (srow & 7)) * 8;   // (srow+32)&7 == srow&7
    const int vs = (slot - srow) & 7;
    const u16* vg0 = vp + (size_t)srow * T_SEQ + vs * 8;
    const u16* vg1 = vp + (size_t)(srow + 32) * T_SEQ + vs * 8;

    auto stage = [&](int j, int buf) {
        const u16* ks = kg0 + j * 64 * HDIM;
        u16* Kd = &Kl[buf][wave * 512];
        GLOAD_LDS16(ks, Kd);
        GLOAD_LDS16(ks + 32 * HDIM, Kd + 2048);
        u16* Vd = &Vl[buf][wave * 512];
        GLOAD_LDS16(vg0 + j * 64, Vd);
        GLOAD_LDS16(vg1 + j * 64, Vd + 2048);
    };

    stage(0, 0);   // prologue: tile 0 -> buffer 0 (async)

    // Q fragments (B-layout): lane l15 holds Q[row][kc*32+quad*8..+7],
    // pre-scaled by scale*log2(e)
    const float SL2E = 0.125f * 1.44269504088896f;
    bf16x8 qf[2];
    {
        const float* qrow = qp + (size_t)(qrow_base + l15) * HDIM;
#pragma unroll
        for (int kc = 0; kc < 2; kc++) {
            const float4* p4 = (const float4*)(qrow + kc * 32 + quad * 8);
            float4 fa = p4[0], fb = p4[1];
            union { bf16x8 v; u16 s[8]; } cv;
            cv.s[0] = f2b_rne(fa.x * SL2E); cv.s[1] = f2b_rne(fa.y * SL2E);
            cv.s[2] = f2b_rne(fa.z * SL2E); cv.s[3] = f2b_rne(fa.w * SL2E);
            cv.s[4] = f2b_rne(fb.x * SL2E); cv.s[5] = f2b_rne(fb.y * SL2E);
            cv.s[6] = f2b_rne(fb.z * SL2E); cv.s[7] = f2b_rne(fb.w * SL2E);
            qf[kc] = cv.v;
        }
    }

    floatx4 o_acc[4];
#pragma unroll
    for (int dt = 0; dt < 4; dt++) o_acc[dt] = (floatx4){0.f, 0.f, 0.f, 0.f};
    float lsum = 0.f;                              // partial row-sum, qrow = l15

    for (int j = 0; j <= qt; ++j) {
        const int cur = j & 1;
        __syncthreads();   // vmcnt drain + barrier: buf[cur] fully staged

        if (j < qt) stage(j + 1, cur ^ 1);         // async prefetch, no wait

        // S^T = K · Q^T : A = K-frag (m=key), B = qf (n=qrow)
        floatx4 sacc[4];
#pragma unroll
        for (int t = 0; t < 4; t++) sacc[t] = (floatx4){0.f, 0.f, 0.f, 0.f};
        const u16* Kc = Kl[cur];
#pragma unroll
        for (int kc = 0; kc < 2; kc++) {
#pragma unroll
            for (int t = 0; t < 4; t++) {
                int rk = t * 16 + l15;
                bf16x8 kf = *(const bf16x8*)(Kc + rk * 64 + ((kc * 4 + quad) ^ (rk & 7)) * 8);
                sacc[t] = __builtin_amdgcn_mfma_f32_16x16x32_bf16(kf, qf[kc], sacc[t], 0, 0, 0);
            }
        }

        // P^T = exp2(S^T), causal mask on diagonal tile, pack to PV A-frags
        s16x4 pfrag[4];
        const bool diag = (j == qt);
        const int gq = wave * 16 + l15;            // q-row within 64-block
#pragma unroll
        for (int t = 0; t < 4; t++) {
            union { s16x4 v; u16 h[4]; } pk;
#pragma unroll
            for (int rg = 0; rg < 4; rg++) {
                float e = __builtin_amdgcn_exp2f(sacc[t][rg]);
                if (diag && (t * 16 + quad * 4 + rg > gq)) e = 0.f;
                lsum += e;
                pk.h[rg] = f2b_trunc(e);
            }
            pfrag[t] = pk.v;
        }

        // O += P · V : A = pfrag (regs), B = V-frags (b128 covers t-pair)
        const u16* Vc = Vl[cur];
#pragma unroll
        for (int tp = 0; tp < 2; tp++) {
#pragma unroll
            for (int dt = 0; dt < 4; dt++) {
                int d = dt * 16 + l15;
                int sl = (quad * 2 + tp + d) & 7;
                s16x8 vf = *(const s16x8*)(Vc + d * 64 + sl * 8);
                s16x4 vf0 = __builtin_shufflevector(vf, vf, 0, 1, 2, 3);
                s16x4 vf1 = __builtin_shufflevector(vf, vf, 4, 5, 6, 7);
                o_acc[dt] = __builtin_amdgcn_mfma_f32_16x16x16bf16_1k(pfrag[2 * tp], vf0, o_acc[dt], 0, 0, 0);
                o_acc[dt] = __builtin_amdgcn_mfma_f32_16x16x16bf16_1k(pfrag[2 * tp + 1], vf1, o_acc[dt], 0, 0, 0);
            }
        }
    }

    // epilogue: reduce lsum over quads, redistribute, store O/l
    float tot = lsum;
    tot += __shfl_xor(tot, 16, 64);
    tot += __shfl_xor(tot, 32, 64);                // lane holds sum for qrow=l15
    float* op = out + (size_t)bh * T_SEQ * HDIM;
#pragma unroll
    for (int rg = 0; rg < 4; rg++) {
        float inv = 1.0f / __shfl(tot, quad * 4 + rg, 64);
        size_t row = (size_t)(qrow_base + quad * 4 + rg) * HDIM;
#pragma unroll
        for (int dt = 0; dt < 4; dt++)
            op[row + dt * 16 + l15] = o_acc[dt][rg] * inv;
    }
}

extern "C" void kernel_launch(void* const* d_in, const int* in_sizes, int n_in,
                              void* d_out, int out_size, void* d_ws, size_t ws_size,
                              hipStream_t stream) {
    const float* q = (const float*)d_in[0];
    const float* k = (const float*)d_in[1];
    const float* v = (const float*)d_in[2];
    float* out = (float*)d_out;

    u16* kb = (u16*)d_ws;                               // 8 MB bf16 K
    u16* vt = kb + (size_t)NBH * T_SEQ * HDIM;          // 8 MB bf16 V^T (permuted)

    prep<<<dim3(T_SEQ / 64, NBH), 256, 0, stream>>>(k, v, kb, vt);
    fattn<<<dim3(NBH, T_SEQ / 64), 256, 0, stream>>>(q, kb, vt, out);
}